// Round 1
// baseline (91495.422 us; speedup 1.0000x reference)
//
#include <hip/hip_runtime.h>
#include <math.h>

#define B 128
#define S 1024
#define F 256
#define H 256
#define G3 768   // 3*H
#define NLAYERS 2

// block covers BB batch rows x KS k-columns; one thread per (b,k) pair
#define BB 8
#define KS 32
// threads per block = BB*KS = 256

__device__ __forceinline__ float sigmoidf_(float v) {
    return 1.0f / (1.0f + __expf(-v));
}

// One time-step for one layer.
// LAYER==0: input = x[:, t, :] * fw * tw[t]   (from global x)
// LAYER==1: input = h0 state (just updated by the LAYER==0 kernel)
template<int LAYER>
__global__ __launch_bounds__(256)
void lstm_step_kernel(const float* __restrict__ x,          // (B,S,F) or unused
                      const float* __restrict__ fw,         // (F) or unused
                      const float* __restrict__ tw,         // (S) or unused
                      const float* __restrict__ Wih,        // (3H, 256) this layer
                      const float* __restrict__ bih,        // (3H)
                      const float* __restrict__ Whh,        // (3H, 256)
                      const float* __restrict__ bhh,        // (3H)
                      const float* __restrict__ h_in_other, // layer1: h0 state (B,H)
                      float* __restrict__ h_state,          // this layer h (B,H)
                      float* __restrict__ c_state,          // this layer c (B,H)
                      float* __restrict__ outbuf,           // layer1: outputs (B,S,H)
                      int t)
{
    __shared__ float sIn[BB][F];   // input vector per batch row
    __shared__ float sH [BB][H];   // recurrent h per batch row

    const int b0  = blockIdx.x * BB;
    const int k0  = blockIdx.y * KS;
    const int tid = threadIdx.x;

    // Stage inputs: BB*F = 2048 floats each for sIn and sH; 256 threads -> 2 float4 each
    const float twt = (LAYER == 0) ? tw[t] : 1.0f;
    for (int idx = tid; idx < BB * (F / 4); idx += 256) {
        const int bi = idx / (F / 4);
        const int f4 = idx % (F / 4);
        float4 v;
        if (LAYER == 0) {
            v = *(const float4*)(x + (size_t)(b0 + bi) * S * F + (size_t)t * F + f4 * 4);
            const float4 w = *(const float4*)(fw + f4 * 4);
            v.x *= w.x * twt; v.y *= w.y * twt; v.z *= w.z * twt; v.w *= w.w * twt;
        } else {
            v = *(const float4*)(h_in_other + (size_t)(b0 + bi) * H + f4 * 4);
        }
        *(float4*)(&sIn[bi][f4 * 4]) = v;
        const float4 hv = *(const float4*)(h_state + (size_t)(b0 + bi) * H + f4 * 4);
        *(float4*)(&sH[bi][f4 * 4]) = hv;
    }
    __syncthreads();

    const int bi = tid / KS;       // 0..BB-1
    const int kj = tid % KS;       // 0..KS-1
    const int k  = k0 + kj;        // hidden index this thread owns
    const int b  = b0 + bi;

    // gate rows: i -> row k ; g -> row H+k ; o -> row 2H+k
    float acc_i = bih[k]         + bhh[k];
    float acc_g = bih[H + k]     + bhh[H + k];
    float acc_o = bih[2 * H + k] + bhh[2 * H + k];

    const float4* wi_i = (const float4*)(Wih + (size_t)k * F);
    const float4* wi_g = (const float4*)(Wih + (size_t)(H + k) * F);
    const float4* wi_o = (const float4*)(Wih + (size_t)(2 * H + k) * F);
    const float4* wh_i = (const float4*)(Whh + (size_t)k * H);
    const float4* wh_g = (const float4*)(Whh + (size_t)(H + k) * H);
    const float4* wh_o = (const float4*)(Whh + (size_t)(2 * H + k) * H);
    const float4* xin  = (const float4*)(&sIn[bi][0]);
    const float4* hin  = (const float4*)(&sH[bi][0]);

    #pragma unroll 8
    for (int f4 = 0; f4 < F / 4; ++f4) {
        const float4 xv = xin[f4];
        const float4 hv = hin[f4];
        float4 w;
        w = wi_i[f4]; acc_i += xv.x * w.x + xv.y * w.y + xv.z * w.z + xv.w * w.w;
        w = wi_g[f4]; acc_g += xv.x * w.x + xv.y * w.y + xv.z * w.z + xv.w * w.w;
        w = wi_o[f4]; acc_o += xv.x * w.x + xv.y * w.y + xv.z * w.z + xv.w * w.w;
        w = wh_i[f4]; acc_i += hv.x * w.x + hv.y * w.y + hv.z * w.z + hv.w * w.w;
        w = wh_g[f4]; acc_g += hv.x * w.x + hv.y * w.y + hv.z * w.z + hv.w * w.w;
        w = wh_o[f4]; acc_o += hv.x * w.x + hv.y * w.y + hv.z * w.z + hv.w * w.w;
    }

    // elementwise cell update (note: forget gate = sigmoid(c_prev) per reference)
    const float cprev = c_state[(size_t)b * H + k];
    const float fg    = sigmoidf_(cprev);
    const float cnew  = fg * cprev + sigmoidf_(acc_i) * tanhf(acc_g);
    const float hnew  = sigmoidf_(acc_o) * tanhf(cnew);

    c_state[(size_t)b * H + k] = cnew;
    h_state[(size_t)b * H + k] = hnew;
    if (LAYER == 1) {
        outbuf[(size_t)b * S * H + (size_t)t * H + k] = hnew;
    }
}

extern "C" void kernel_launch(void* const* d_in, const int* in_sizes, int n_in,
                              void* d_out, int out_size, void* d_ws, size_t ws_size,
                              hipStream_t stream) {
    const float* x   = (const float*)d_in[0];
    const float* fw  = (const float*)d_in[1];
    const float* tw  = (const float*)d_in[2];
    const float* Wih = (const float*)d_in[3];  // (L, 3H, F)
    const float* bih = (const float*)d_in[4];  // (L, 3H)
    const float* Whh = (const float*)d_in[5];  // (L, 3H, H)
    const float* bhh = (const float*)d_in[6];  // (L, 3H)

    float* out     = (float*)d_out;
    float* outputs = out;                                  // (B,S,H)
    float* hs      = out + (size_t)B * S * H;              // (L,B,H)
    float* cs      = hs + (size_t)NLAYERS * B * H;         // (L,B,H)

    // workspace: h0, c0, h1, c1 states, each (B,H)
    float* ws = (float*)d_ws;
    float* h0 = ws;
    float* c0 = h0 + (size_t)B * H;
    float* h1 = c0 + (size_t)B * H;
    float* c1 = h1 + (size_t)B * H;

    hipMemsetAsync(ws, 0, (size_t)4 * B * H * sizeof(float), stream);

    const dim3 grid(B / BB, H / KS);
    const dim3 block(BB * KS);

    const float* Wih1 = Wih + (size_t)G3 * F;
    const float* bih1 = bih + G3;
    const float* Whh1 = Whh + (size_t)G3 * H;
    const float* bhh1 = bhh + G3;

    for (int t = 0; t < S; ++t) {
        lstm_step_kernel<0><<<grid, block, 0, stream>>>(
            x, fw, tw, Wih, bih, Whh, bhh,
            nullptr, h0, c0, nullptr, t);
        lstm_step_kernel<1><<<grid, block, 0, stream>>>(
            nullptr, nullptr, nullptr, Wih1, bih1, Whh1, bhh1,
            h0, h1, c1, outputs, t);
    }

    // final per-layer states
    hipMemcpyAsync(hs,           h0, (size_t)B * H * sizeof(float), hipMemcpyDeviceToDevice, stream);
    hipMemcpyAsync(hs + B * H,   h1, (size_t)B * H * sizeof(float), hipMemcpyDeviceToDevice, stream);
    hipMemcpyAsync(cs,           c0, (size_t)B * H * sizeof(float), hipMemcpyDeviceToDevice, stream);
    hipMemcpyAsync(cs + B * H,   c1, (size_t)B * H * sizeof(float), hipMemcpyDeviceToDevice, stream);
}

// Round 2
// 30343.539 us; speedup vs baseline: 3.0153x; 3.0153x over previous
//
#include <hip/hip_runtime.h>
#include <math.h>

#define B 128
#define S 1024
#define F 256
#define H 256
#define G3 768
#define NBLK 256          // total blocks: 128 per layer
#define NTHR 256
#define UNITS_PER_BLK 8   // hidden units per block
#define BB 32             // batch per block
#define NPHASE (S + 1)

// ws layout: [0,16KB) barrier counters (1024 phases x 4 domains), then h0 double buffer
#define CTR_SLOTS (1024 * 4)
#define CTR_BYTES (CTR_SLOTS * 4)

__device__ __forceinline__ float sigf(float v) { return 1.0f / (1.0f + __expf(-v)); }

__global__ __launch_bounds__(NTHR)
void lstm_persist(const float* __restrict__ x,    // (B,S,F)
                  const float* __restrict__ fw,   // (F)
                  const float* __restrict__ tw,   // (S)
                  const float* __restrict__ Wih,  // (L,3H,F)
                  const float* __restrict__ bih,  // (L,3H)
                  const float* __restrict__ Whh,  // (L,3H,H)
                  const float* __restrict__ bhh,  // (L,3H)
                  float* __restrict__ out,        // outputs | hs | cs
                  void* __restrict__ ws)
{
    __shared__ float sW[UNITS_PER_BLK * 3 * 512]; // 24 rows x 512 (Wih|Whh)  = 48 KB
    __shared__ float sB[32];                      // 24 biases (bih+bhh)
    __shared__ float sIn[512 * BB];               // input tile [k][b]        = 64 KB

    unsigned* ctr  = (unsigned*)ws;
    float* h0buf   = (float*)((char*)ws + CTR_BYTES);   // 2 x (B,H)
    float* outputs = out;                               // (B,S,H)
    float* hs      = out + (size_t)B * S * H;           // (L,B,H)
    float* cs      = hs + (size_t)2 * B * H;            // (L,B,H)

    const int bid   = blockIdx.x;
    const int tid   = threadIdx.x;
    const int layer = bid >> 7;        // 0..1
    const int r     = bid & 127;
    const int ug    = r >> 2;          // unit group 0..31
    const int bg    = r & 3;           // batch group 0..3 (barrier domain)
    const int gb0   = bg * BB;

    const int u  = tid >> 5;           // 0..7  local unit
    const int bb = tid & 31;           // 0..31 local batch
    const int kh = ug * UNITS_PER_BLK + u;  // global hidden index
    const int bglob = gb0 + bb;

    const float* Wih_l = Wih + (size_t)layer * G3 * F;
    const float* Whh_l = Whh + (size_t)layer * G3 * H;

    // ---- stage weights once: row j = s*8+uu -> global gate row s*256 + ug*8 + uu ----
    for (int idx = tid; idx < 24 * 128; idx += NTHR) {
        const int j = idx >> 7;          // 0..23
        const int q = idx & 127;         // float4 index within 512
        const int s = j >> 3, uu = j & 7;
        const int grow = s * H + ug * UNITS_PER_BLK + uu;
        float4 v;
        if (q < 64) v = *(const float4*)(Wih_l + (size_t)grow * F + q * 4);
        else        v = *(const float4*)(Whh_l + (size_t)grow * H + (q - 64) * 4);
        *(float4*)(sW + (size_t)j * 512 + q * 4) = v;
    }
    if (tid < 24) {
        const int s = tid >> 3, uu = tid & 7;
        const int grow = s * H + ug * UNITS_PER_BLK + uu;
        sB[tid] = bih[layer * G3 + grow] + bhh[layer * G3 + grow];
    }
    __syncthreads();

    float c_reg = 0.0f;

    const float* w0 = sW + (size_t)(0 * 8 + u) * 512;  // i row
    const float* w1 = sW + (size_t)(1 * 8 + u) * 512;  // g row
    const float* w2 = sW + (size_t)(2 * 8 + u) * 512;  // o row
    const float* inb = sIn + bb;

    for (int p = 0; p < NPHASE; ++p) {
        const bool active = (layer == 0) ? (p < S) : (p >= 1);
        const int prev = (p + 1) & 1;   // parity of phase p-1
        const int t0 = p;               // layer0 time
        const int t1 = p - 1;           // layer1 time

        if (active) {
            const float twt = (layer == 0) ? tw[t0] : 0.0f;
            // stage input tile: sIn[k][b], k<256 = layer input, k>=256 = recurrent h
            for (int idx = tid; idx < BB * 128; idx += NTHR) {
                const int b_ = idx & 31;
                const int k4 = idx >> 5;       // 0..127
                const int k  = k4 << 2;
                float4 v;
                if (layer == 0) {
                    if (k < 256) {
                        v = *(const float4*)(x + ((size_t)(gb0 + b_) * S + t0) * F + k);
                        const float4 fwv = *(const float4*)(fw + k);
                        v.x *= fwv.x * twt; v.y *= fwv.y * twt;
                        v.z *= fwv.z * twt; v.w *= fwv.w * twt;
                    } else {
                        v = *(const float4*)(h0buf + (size_t)prev * B * H +
                                             (size_t)(gb0 + b_) * H + (k - 256));
                    }
                } else {
                    if (k < 256) {
                        v = *(const float4*)(h0buf + (size_t)prev * B * H +
                                             (size_t)(gb0 + b_) * H + k);
                    } else if (t1 >= 1) {
                        v = *(const float4*)(outputs + ((size_t)(gb0 + b_) * S + (t1 - 1)) * H +
                                             (k - 256));
                    } else {
                        v = make_float4(0.f, 0.f, 0.f, 0.f);
                    }
                }
                sIn[(k + 0) * BB + b_] = v.x;
                sIn[(k + 1) * BB + b_] = v.y;
                sIn[(k + 2) * BB + b_] = v.z;
                sIn[(k + 3) * BB + b_] = v.w;
            }
        }
        __syncthreads();

        if (active) {
            float acc0 = sB[u];
            float acc1 = sB[8 + u];
            float acc2 = sB[16 + u];
            #pragma unroll 4
            for (int k = 0; k < 512; k += 4) {
                const float i0 = inb[(k + 0) * BB];
                const float i1 = inb[(k + 1) * BB];
                const float i2 = inb[(k + 2) * BB];
                const float i3 = inb[(k + 3) * BB];
                const float4 a = *(const float4*)(w0 + k);
                const float4 b4 = *(const float4*)(w1 + k);
                const float4 c4 = *(const float4*)(w2 + k);
                acc0 += i0 * a.x + i1 * a.y + i2 * a.z + i3 * a.w;
                acc1 += i0 * b4.x + i1 * b4.y + i2 * b4.z + i3 * b4.w;
                acc2 += i0 * c4.x + i1 * c4.y + i2 * c4.z + i3 * c4.w;
            }
            // cell update: f = sigmoid(c_prev)
            const float fg = sigf(c_reg);
            const float cn = fg * c_reg + sigf(acc0) * tanhf(acc1);
            const float hn = sigf(acc2) * tanhf(cn);
            c_reg = cn;

            if (layer == 0) {
                h0buf[(size_t)(p & 1) * B * H + (size_t)bglob * H + kh] = hn;
                if (p == S - 1) {
                    hs[(size_t)bglob * H + kh] = hn;
                    cs[(size_t)bglob * H + kh] = c_reg;
                }
            } else {
                outputs[((size_t)bglob * S + t1) * H + kh] = hn;
                if (p == S) {
                    hs[(size_t)B * H + (size_t)bglob * H + kh] = hn;
                    cs[(size_t)B * H + (size_t)bglob * H + kh] = c_reg;
                }
            }
        }

        // domain barrier (64 blocks sharing this batch group), phases 0..1023
        if (p < S) {
            __syncthreads();
            if (tid == 0) {
                const int slot = p * 4 + bg;
                __threadfence();                 // release our h writes
                atomicAdd(&ctr[slot], 1u);       // device-scope by default
                while (__hip_atomic_load(&ctr[slot], __ATOMIC_RELAXED,
                                         __HIP_MEMORY_SCOPE_AGENT) < 64u) {
                    __builtin_amdgcn_s_sleep(1);
                }
                __threadfence();                 // acquire: invalidate caches
            }
            __syncthreads();
        }
    }
}

extern "C" void kernel_launch(void* const* d_in, const int* in_sizes, int n_in,
                              void* d_out, int out_size, void* d_ws, size_t ws_size,
                              hipStream_t stream) {
    const float* x   = (const float*)d_in[0];
    const float* fw  = (const float*)d_in[1];
    const float* tw  = (const float*)d_in[2];
    const float* Wih = (const float*)d_in[3];
    const float* bih = (const float*)d_in[4];
    const float* Whh = (const float*)d_in[5];
    const float* bhh = (const float*)d_in[6];
    float* out = (float*)d_out;

    // zero barrier counters + h0 double buffer every call (graph replays reuse ws!)
    const size_t zero_bytes = CTR_BYTES + (size_t)2 * B * H * sizeof(float);
    hipMemsetAsync(d_ws, 0, zero_bytes, stream);

    void* kargs[] = { (void*)&x, (void*)&fw, (void*)&tw, (void*)&Wih, (void*)&bih,
                      (void*)&Whh, (void*)&bhh, (void*)&out, (void*)&d_ws };
    hipError_t e = hipLaunchCooperativeKernel((const void*)lstm_persist,
                                              dim3(NBLK), dim3(NTHR),
                                              kargs, 0, stream);
    if (e != hipSuccess) {
        // fallback: plain launch (kernel uses only device-scope atomics; 1 block/CU
        // at 114KB LDS so all 256 blocks are co-resident on a 256-CU MI355X)
        lstm_persist<<<dim3(NBLK), dim3(NTHR), 0, stream>>>(
            x, fw, tw, Wih, bih, Whh, bhh, out, d_ws);
    }
}

// Round 3
// 11322.748 us; speedup vs baseline: 8.0807x; 2.6799x over previous
//
#include <hip/hip_runtime.h>
#include <math.h>

#define B_ 128
#define S_ 1024
#define F_ 256
#define H_ 256
#define G3 768

#define UG 8        // unit-groups per layer (32 units each)
#define UNITS 32
#define M_ROWS 96   // 3 gates * 32 units
#define BGROUPS 4
#define BB 32
#define NBLK (BGROUPS * 2 * UG)   // 64 blocks
#define NTHR 256
#define NPHASE (S_ + 1)
#define DOMAIN_BLOCKS (2 * UG)    // 16 blocks per barrier domain

#define CTR_SLOTS (S_ * BGROUPS)
#define CTR_BYTES (CTR_SLOTS * 4)

typedef __bf16 bf16x8 __attribute__((ext_vector_type(8)));
typedef float f32x4 __attribute__((ext_vector_type(4)));
typedef unsigned short us8 __attribute__((ext_vector_type(8)));

__device__ __forceinline__ float sigf(float v) { return 1.0f / (1.0f + __expf(-v)); }
__device__ __forceinline__ unsigned short f2bf(float f) {
    unsigned u = __builtin_bit_cast(unsigned, f);
    return (unsigned short)((u + 0x7fffu + ((u >> 16) & 1u)) >> 16);   // RNE
}

__global__ __launch_bounds__(NTHR)
void lstm_mfma(const float* __restrict__ x,    // (B,S,F)
               const float* __restrict__ fw,   // (F)
               const float* __restrict__ tw,   // (S)
               const float* __restrict__ Wih,  // (L,3H,F)
               const float* __restrict__ bih,  // (L,3H)
               const float* __restrict__ Whh,  // (L,3H,H)
               const float* __restrict__ bhh,  // (L,3H)
               float* __restrict__ out,        // outputs | hs | cs
               void* __restrict__ ws)
{
    // fragment-ordered bf16 weights: [mt(6)][kt(16)][lane(64)][8 bf16]
    __shared__ unsigned short sW[6 * 16 * 64 * 8];     // 96 KB
    // fragment-ordered bf16 inputs: [kt(16)][nt(2)][lane(64)][8 bf16]
    __shared__ unsigned short sIn[16 * 2 * 64 * 8];    // 32 KB
    __shared__ float sG[M_ROWS][BB + 1];               // gates fp32, padded
    __shared__ float sB[M_ROWS];

    unsigned* ctr = (unsigned*)ws;
    float* hbuf   = (float*)((char*)ws + CTR_BYTES);   // [layer][parity][B][H]
    float* outputs = out;
    float* hs = out + (size_t)B_ * S_ * H_;
    float* cs = hs + (size_t)2 * B_ * H_;

    const int bid   = blockIdx.x;
    const int tid   = threadIdx.x;
    const int ug    = bid & 7;
    const int layer = (bid >> 3) & 1;
    const int bg    = bid >> 4;
    const int gb0   = bg * BB;

    const int lane = tid & 63;
    const int wave = tid >> 6;
    const int ntw  = wave & 1;          // ntile (batch 16-half)
    const int m0   = (wave >> 1) * 3;   // first mtile (of 16 rows)

    const float* Wih_l = Wih + (size_t)layer * G3 * F_;
    const float* Whh_l = Whh + (size_t)layer * G3 * H_;

    // ---- stage weights once into fragment order (bf16) ----
    // A-frag layout (16x16x32): lane holds A[mt*16 + (l&15)][kt*32 + (l>>4)*8 + j]
    for (int idx = tid; idx < 6 * 16 * 64; idx += NTHR) {
        const int l   = idx & 63;
        const int kt  = (idx >> 6) & 15;
        const int mt  = idx >> 10;
        const int row = mt * 16 + (l & 15);              // local gate row 0..95
        const int k   = kt * 32 + (l >> 4) * 8;          // 0..504
        const int grow = (row >> 5) * H_ + ug * UNITS + (row & 31);
        const float* src = (k < 256) ? (Wih_l + (size_t)grow * F_ + k)
                                     : (Whh_l + (size_t)grow * H_ + (k - 256));
        float4 a = *(const float4*)src;
        float4 b = *(const float4*)(src + 4);
        us8 w;
        w[0] = f2bf(a.x); w[1] = f2bf(a.y); w[2] = f2bf(a.z); w[3] = f2bf(a.w);
        w[4] = f2bf(b.x); w[5] = f2bf(b.y); w[6] = f2bf(b.z); w[7] = f2bf(b.w);
        *(us8*)&sW[(size_t)idx * 8] = w;
    }
    if (tid < M_ROWS) {
        const int grow = (tid >> 5) * H_ + ug * UNITS + (tid & 31);
        sB[tid] = bih[layer * G3 + grow] + bhh[layer * G3 + grow];
    }
    __syncthreads();

    float c_reg[4] = {0.f, 0.f, 0.f, 0.f};
    const int uu = tid & 31;   // update: unit
    const int bq = tid >> 5;   // update: batch sub-index

    for (int p = 0; p < NPHASE; ++p) {
        const bool active = (layer == 0) ? (p < S_) : (p >= 1);
        const int par  = p & 1;
        const int prev = par ^ 1;
        const int t    = (layer == 0) ? p : (p - 1);
        float* hb_own            = hbuf + ((size_t)layer * 2 + par)  * B_ * H_;
        const float* hb_own_prev = hbuf + ((size_t)layer * 2 + prev) * B_ * H_;
        const float* hb_l0_prev  = hbuf + ((size_t)prev)             * B_ * H_;

        if (active) {
            const float twt = (layer == 0) ? tw[t] : 0.f;
            // B-frag layout: lane holds X[kt*32 + (l>>4)*8 + j][nt*16 + (l&15)]
            for (int idx = tid; idx < 16 * 2 * 64; idx += NTHR) {
                const int l  = idx & 63;
                const int nt = (idx >> 6) & 1;
                const int kt = idx >> 7;
                const int bcol  = nt * 16 + (l & 15);
                const int k     = kt * 32 + (l >> 4) * 8;
                const int bglob = gb0 + bcol;
                float4 a, b;
                if (layer == 0) {
                    if (k < 256) {
                        const float* src = x + ((size_t)bglob * S_ + t) * F_ + k;
                        a = *(const float4*)src; b = *(const float4*)(src + 4);
                        const float4 w1 = *(const float4*)(fw + k);
                        const float4 w2 = *(const float4*)(fw + k + 4);
                        a.x *= w1.x * twt; a.y *= w1.y * twt;
                        a.z *= w1.z * twt; a.w *= w1.w * twt;
                        b.x *= w2.x * twt; b.y *= w2.y * twt;
                        b.z *= w2.z * twt; b.w *= w2.w * twt;
                    } else {
                        const float* src = hb_own_prev + (size_t)bglob * H_ + (k - 256);
                        a = *(const float4*)src; b = *(const float4*)(src + 4);
                    }
                } else {
                    const float* src = (k < 256)
                        ? (hb_l0_prev  + (size_t)bglob * H_ + k)
                        : (hb_own_prev + (size_t)bglob * H_ + (k - 256));
                    a = *(const float4*)src; b = *(const float4*)(src + 4);
                }
                us8 w;
                w[0] = f2bf(a.x); w[1] = f2bf(a.y); w[2] = f2bf(a.z); w[3] = f2bf(a.w);
                w[4] = f2bf(b.x); w[5] = f2bf(b.y); w[6] = f2bf(b.z); w[7] = f2bf(b.w);
                *(us8*)&sIn[(size_t)idx * 8] = w;
            }
        }
        __syncthreads();

        if (active) {
            f32x4 acc0 = {0.f, 0.f, 0.f, 0.f};
            f32x4 acc1 = {0.f, 0.f, 0.f, 0.f};
            f32x4 acc2 = {0.f, 0.f, 0.f, 0.f};
            #pragma unroll
            for (int kt = 0; kt < 16; ++kt) {
                const bf16x8 bfr = *(const bf16x8*)&sIn[((kt * 2 + ntw) * 64 + lane) * 8];
                const bf16x8 a0 = *(const bf16x8*)&sW[(((m0 + 0) * 16 + kt) * 64 + lane) * 8];
                const bf16x8 a1 = *(const bf16x8*)&sW[(((m0 + 1) * 16 + kt) * 64 + lane) * 8];
                const bf16x8 a2 = *(const bf16x8*)&sW[(((m0 + 2) * 16 + kt) * 64 + lane) * 8];
                acc0 = __builtin_amdgcn_mfma_f32_16x16x32_bf16(a0, bfr, acc0, 0, 0, 0);
                acc1 = __builtin_amdgcn_mfma_f32_16x16x32_bf16(a1, bfr, acc1, 0, 0, 0);
                acc2 = __builtin_amdgcn_mfma_f32_16x16x32_bf16(a2, bfr, acc2, 0, 0, 0);
            }
            // C/D layout: col = lane&15, row = (lane>>4)*4 + reg
            const int crow = (lane >> 4) * 4;
            const int ccol = ntw * 16 + (lane & 15);
            #pragma unroll
            for (int r = 0; r < 4; ++r) {
                sG[(m0 + 0) * 16 + crow + r][ccol] = acc0[r];
                sG[(m0 + 1) * 16 + crow + r][ccol] = acc1[r];
                sG[(m0 + 2) * 16 + crow + r][ccol] = acc2[r];
            }
        }
        __syncthreads();

        if (active) {
            #pragma unroll
            for (int q = 0; q < 4; ++q) {
                const int b = q * 8 + bq;
                const float gi = sG[uu][b]      + sB[uu];
                const float gg = sG[32 + uu][b] + sB[32 + uu];
                const float go = sG[64 + uu][b] + sB[64 + uu];
                const float cp = c_reg[q];
                const float fg = sigf(cp);                 // forget = sigmoid(c_prev)
                const float cn = fg * cp + sigf(gi) * tanhf(gg);
                const float hn = sigf(go) * tanhf(cn);
                c_reg[q] = cn;
                const int bglob = gb0 + b;
                const int hg = ug * UNITS + uu;
                hb_own[(size_t)bglob * H_ + hg] = hn;
                if (layer == 1)
                    outputs[((size_t)bglob * S_ + t) * H_ + hg] = hn;
                if ((layer == 0 && p == S_ - 1) || (layer == 1 && p == S_)) {
                    hs[(size_t)layer * B_ * H_ + (size_t)bglob * H_ + hg] = hn;
                    cs[(size_t)layer * B_ * H_ + (size_t)bglob * H_ + hg] = cn;
                }
            }
        }

        // inter-block barrier per batch-group domain (16 blocks)
        if (p < S_) {
            __syncthreads();
            if (tid == 0) {
                const int slot = p * BGROUPS + bg;
                __threadfence();                 // release h writes (wbl2)
                atomicAdd(&ctr[slot], 1u);
                while (__hip_atomic_load(&ctr[slot], __ATOMIC_RELAXED,
                                         __HIP_MEMORY_SCOPE_AGENT) < DOMAIN_BLOCKS)
                    __builtin_amdgcn_s_sleep(1);
                __threadfence();                 // acquire
            }
            __syncthreads();
        }
    }
}

extern "C" void kernel_launch(void* const* d_in, const int* in_sizes, int n_in,
                              void* d_out, int out_size, void* d_ws, size_t ws_size,
                              hipStream_t stream) {
    const float* x   = (const float*)d_in[0];
    const float* fw  = (const float*)d_in[1];
    const float* tw  = (const float*)d_in[2];
    const float* Wih = (const float*)d_in[3];
    const float* bih = (const float*)d_in[4];
    const float* Whh = (const float*)d_in[5];
    const float* bhh = (const float*)d_in[6];
    float* out = (float*)d_out;

    // zero barrier counters + h exchange buffers every call (graph-replay safe)
    const size_t zero_bytes = CTR_BYTES + (size_t)4 * B_ * H_ * sizeof(float);
    hipMemsetAsync(d_ws, 0, zero_bytes, stream);

    void* kargs[] = { (void*)&x, (void*)&fw, (void*)&tw, (void*)&Wih, (void*)&bih,
                      (void*)&Whh, (void*)&bhh, (void*)&out, (void*)&d_ws };
    hipError_t e = hipLaunchCooperativeKernel((const void*)lstm_mfma,
                                              dim3(NBLK), dim3(NTHR),
                                              kargs, 0, stream);
    if (e != hipSuccess) {
        // fallback: plain launch; 64 blocks at 1 block/CU (LDS-bound) on 256 CUs
        // are trivially co-resident; only device-scope atomics used.
        lstm_mfma<<<dim3(NBLK), dim3(NTHR), 0, stream>>>(
            x, fw, tw, Wih, bih, Whh, bhh, out, d_ws);
    }
}

// Round 4
// 9601.052 us; speedup vs baseline: 9.5297x; 1.1793x over previous
//
#include <hip/hip_runtime.h>
#include <math.h>

#define B_ 128
#define S_ 1024
#define F_ 256
#define H_ 256
#define G3 768

#define UG 8        // unit-groups per layer (32 units each)
#define UNITS 32
#define M_ROWS 96   // 3 gates * 32 units
#define BGROUPS 4
#define BB 32
#define NBLK (BGROUPS * 2 * UG)   // 64 blocks
#define NTHR 256
#define NPHASE (S_ + 1)
#define DOMAIN_BLOCKS (2 * UG)    // 16 blocks per barrier domain

#define CTR_SLOTS (S_ * BGROUPS)
#define CTR_BYTES (CTR_SLOTS * 4)

typedef __bf16 bf16x8 __attribute__((ext_vector_type(8)));
typedef float f32x4 __attribute__((ext_vector_type(4)));
typedef unsigned short us8 __attribute__((ext_vector_type(8)));

__device__ __forceinline__ float sigf(float v) { return 1.0f / (1.0f + __expf(-v)); }
__device__ __forceinline__ unsigned short f2bf(float f) {
    unsigned u = __builtin_bit_cast(unsigned, f);
    return (unsigned short)((u + 0x7fffu + ((u >> 16) & 1u)) >> 16);   // RNE
}

// 8 consecutive floats via 4x relaxed agent-scope (device-coherent, L2-bypass)
// 64-bit atomic loads — cross-XCD safe without any cache-invalidate fence.
__device__ __forceinline__ void load8_coh(const float* src, float4& a, float4& b) {
    unsigned long long* p = (unsigned long long*)src;
    const unsigned long long q0 = __hip_atomic_load(p + 0, __ATOMIC_RELAXED, __HIP_MEMORY_SCOPE_AGENT);
    const unsigned long long q1 = __hip_atomic_load(p + 1, __ATOMIC_RELAXED, __HIP_MEMORY_SCOPE_AGENT);
    const unsigned long long q2 = __hip_atomic_load(p + 2, __ATOMIC_RELAXED, __HIP_MEMORY_SCOPE_AGENT);
    const unsigned long long q3 = __hip_atomic_load(p + 3, __ATOMIC_RELAXED, __HIP_MEMORY_SCOPE_AGENT);
    a.x = __builtin_bit_cast(float, (unsigned)q0);
    a.y = __builtin_bit_cast(float, (unsigned)(q0 >> 32));
    a.z = __builtin_bit_cast(float, (unsigned)q1);
    a.w = __builtin_bit_cast(float, (unsigned)(q1 >> 32));
    b.x = __builtin_bit_cast(float, (unsigned)q2);
    b.y = __builtin_bit_cast(float, (unsigned)(q2 >> 32));
    b.z = __builtin_bit_cast(float, (unsigned)q3);
    b.w = __builtin_bit_cast(float, (unsigned)(q3 >> 32));
}

__device__ __forceinline__ void store_coh(float* dst, float v) {
    __hip_atomic_store(dst, v, __ATOMIC_RELAXED, __HIP_MEMORY_SCOPE_AGENT);
}

__global__ __launch_bounds__(NTHR)
void lstm_mfma(const float* __restrict__ x,    // (B,S,F)
               const float* __restrict__ fw,   // (F)
               const float* __restrict__ tw,   // (S)
               const float* __restrict__ Wih,  // (L,3H,F)
               const float* __restrict__ bih,  // (L,3H)
               const float* __restrict__ Whh,  // (L,3H,H)
               const float* __restrict__ bhh,  // (L,3H)
               float* __restrict__ out,        // outputs | hs | cs
               void* __restrict__ ws)
{
    // fragment-ordered bf16 weights: [mt(6)][kt(16)][lane(64)][8 bf16]
    __shared__ unsigned short sW[6 * 16 * 64 * 8];     // 96 KB
    // fragment-ordered bf16 inputs: [kt(16)][nt(2)][lane(64)][8 bf16]
    __shared__ unsigned short sIn[16 * 2 * 64 * 8];    // 32 KB
    __shared__ float sG[M_ROWS][BB + 1];               // gates fp32, padded
    __shared__ float sB[M_ROWS];

    unsigned* ctr = (unsigned*)ws;
    float* hbuf   = (float*)((char*)ws + CTR_BYTES);   // [layer][parity][B][H]
    float* outputs = out;
    float* hs = out + (size_t)B_ * S_ * H_;
    float* cs = hs + (size_t)2 * B_ * H_;

    const int bid   = blockIdx.x;
    const int tid   = threadIdx.x;
    const int ug    = bid & 7;
    const int layer = (bid >> 3) & 1;
    const int bg    = bid >> 4;
    const int gb0   = bg * BB;

    const int lane = tid & 63;
    const int wave = tid >> 6;
    const int ntw  = wave & 1;          // ntile (batch 16-half)
    const int m0   = (wave >> 1) * 3;   // first mtile (of 16 rows)

    const float* Wih_l = Wih + (size_t)layer * G3 * F_;
    const float* Whh_l = Whh + (size_t)layer * G3 * H_;

    // ---- stage weights once into fragment order (bf16) ----
    // A-frag layout (16x16x32): lane holds A[mt*16 + (l&15)][kt*32 + (l>>4)*8 + j]
    for (int idx = tid; idx < 6 * 16 * 64; idx += NTHR) {
        const int l   = idx & 63;
        const int kt  = (idx >> 6) & 15;
        const int mt  = idx >> 10;
        const int row = mt * 16 + (l & 15);              // local gate row 0..95
        const int k   = kt * 32 + (l >> 4) * 8;          // 0..504
        const int grow = (row >> 5) * H_ + ug * UNITS + (row & 31);
        const float* src = (k < 256) ? (Wih_l + (size_t)grow * F_ + k)
                                     : (Whh_l + (size_t)grow * H_ + (k - 256));
        float4 a = *(const float4*)src;
        float4 b = *(const float4*)(src + 4);
        us8 w;
        w[0] = f2bf(a.x); w[1] = f2bf(a.y); w[2] = f2bf(a.z); w[3] = f2bf(a.w);
        w[4] = f2bf(b.x); w[5] = f2bf(b.y); w[6] = f2bf(b.z); w[7] = f2bf(b.w);
        *(us8*)&sW[(size_t)idx * 8] = w;
    }
    if (tid < M_ROWS) {
        const int grow = (tid >> 5) * H_ + ug * UNITS + (tid & 31);
        sB[tid] = bih[layer * G3 + grow] + bhh[layer * G3 + grow];
    }
    __syncthreads();

    float c_reg[4] = {0.f, 0.f, 0.f, 0.f};
    const int uu = tid & 31;   // update: unit
    const int bq = tid >> 5;   // update: batch sub-index

    for (int p = 0; p < NPHASE; ++p) {
        const bool active = (layer == 0) ? (p < S_) : (p >= 1);
        const int par  = p & 1;
        const int prev = par ^ 1;
        const int t    = (layer == 0) ? p : (p - 1);
        float* hb_own            = hbuf + ((size_t)layer * 2 + par)  * B_ * H_;
        const float* hb_own_prev = hbuf + ((size_t)layer * 2 + prev) * B_ * H_;
        const float* hb_l0_prev  = hbuf + ((size_t)prev)             * B_ * H_;

        if (active) {
            const float twt = (layer == 0) ? tw[t] : 0.f;
            // B-frag layout: lane holds X[kt*32 + (l>>4)*8 + j][nt*16 + (l&15)]
            for (int idx = tid; idx < 16 * 2 * 64; idx += NTHR) {
                const int l  = idx & 63;
                const int nt = (idx >> 6) & 1;
                const int kt = idx >> 7;
                const int bcol  = nt * 16 + (l & 15);
                const int k     = kt * 32 + (l >> 4) * 8;
                const int bglob = gb0 + bcol;
                float4 a, b;
                if (layer == 0) {
                    if (k < 256) {
                        const float* src = x + ((size_t)bglob * S_ + t) * F_ + k;
                        a = *(const float4*)src; b = *(const float4*)(src + 4);
                        const float4 w1 = *(const float4*)(fw + k);
                        const float4 w2 = *(const float4*)(fw + k + 4);
                        a.x *= w1.x * twt; a.y *= w1.y * twt;
                        a.z *= w1.z * twt; a.w *= w1.w * twt;
                        b.x *= w2.x * twt; b.y *= w2.y * twt;
                        b.z *= w2.z * twt; b.w *= w2.w * twt;
                    } else {
                        load8_coh(hb_own_prev + (size_t)bglob * H_ + (k - 256), a, b);
                    }
                } else {
                    const float* src = (k < 256)
                        ? (hb_l0_prev  + (size_t)bglob * H_ + k)
                        : (hb_own_prev + (size_t)bglob * H_ + (k - 256));
                    load8_coh(src, a, b);
                }
                us8 w;
                w[0] = f2bf(a.x); w[1] = f2bf(a.y); w[2] = f2bf(a.z); w[3] = f2bf(a.w);
                w[4] = f2bf(b.x); w[5] = f2bf(b.y); w[6] = f2bf(b.z); w[7] = f2bf(b.w);
                *(us8*)&sIn[(size_t)idx * 8] = w;
            }
        }
        __syncthreads();

        if (active) {
            f32x4 acc0 = {0.f, 0.f, 0.f, 0.f};
            f32x4 acc1 = {0.f, 0.f, 0.f, 0.f};
            f32x4 acc2 = {0.f, 0.f, 0.f, 0.f};
            #pragma unroll
            for (int kt = 0; kt < 16; ++kt) {
                const bf16x8 bfr = *(const bf16x8*)&sIn[((kt * 2 + ntw) * 64 + lane) * 8];
                const bf16x8 a0 = *(const bf16x8*)&sW[(((m0 + 0) * 16 + kt) * 64 + lane) * 8];
                const bf16x8 a1 = *(const bf16x8*)&sW[(((m0 + 1) * 16 + kt) * 64 + lane) * 8];
                const bf16x8 a2 = *(const bf16x8*)&sW[(((m0 + 2) * 16 + kt) * 64 + lane) * 8];
                acc0 = __builtin_amdgcn_mfma_f32_16x16x32_bf16(a0, bfr, acc0, 0, 0, 0);
                acc1 = __builtin_amdgcn_mfma_f32_16x16x32_bf16(a1, bfr, acc1, 0, 0, 0);
                acc2 = __builtin_amdgcn_mfma_f32_16x16x32_bf16(a2, bfr, acc2, 0, 0, 0);
            }
            // C/D layout: col = lane&15, row = (lane>>4)*4 + reg
            const int crow = (lane >> 4) * 4;
            const int ccol = ntw * 16 + (lane & 15);
            #pragma unroll
            for (int r = 0; r < 4; ++r) {
                sG[(m0 + 0) * 16 + crow + r][ccol] = acc0[r];
                sG[(m0 + 1) * 16 + crow + r][ccol] = acc1[r];
                sG[(m0 + 2) * 16 + crow + r][ccol] = acc2[r];
            }
        }
        __syncthreads();

        if (active) {
            #pragma unroll
            for (int q = 0; q < 4; ++q) {
                const int b = q * 8 + bq;
                const float gi = sG[uu][b]      + sB[uu];
                const float gg = sG[32 + uu][b] + sB[32 + uu];
                const float go = sG[64 + uu][b] + sB[64 + uu];
                const float cp = c_reg[q];
                const float fg = sigf(cp);                 // forget = sigmoid(c_prev)
                const float cn = fg * cp + sigf(gi) * tanhf(gg);
                const float hn = sigf(go) * tanhf(cn);
                c_reg[q] = cn;
                const int bglob = gb0 + b;
                const int hg = ug * UNITS + uu;
                store_coh(hb_own + (size_t)bglob * H_ + hg, hn);  // device-coherent
                if (layer == 1)
                    outputs[((size_t)bglob * S_ + t) * H_ + hg] = hn;
                if ((layer == 0 && p == S_ - 1) || (layer == 1 && p == S_)) {
                    hs[(size_t)layer * B_ * H_ + (size_t)bglob * H_ + hg] = hn;
                    cs[(size_t)layer * B_ * H_ + (size_t)bglob * H_ + hg] = cn;
                }
            }
        }

        // inter-block barrier per batch-group domain (16 blocks).
        // No threadfence: h-exchange data is written with agent-scope
        // (coherence-point) stores; __syncthreads drains all waves' vmcnt
        // (compiler emits s_waitcnt vmcnt(0) before s_barrier), so once we
        // arrive, our h values are visible at L3 to all XCDs.
        if (p < S_) {
            __syncthreads();
            if (tid == 0) {
                const int slot = p * BGROUPS + bg;
                asm volatile("s_waitcnt vmcnt(0)" ::: "memory");
                __hip_atomic_fetch_add(&ctr[slot], 1u, __ATOMIC_RELAXED,
                                       __HIP_MEMORY_SCOPE_AGENT);
                while (__hip_atomic_load(&ctr[slot], __ATOMIC_RELAXED,
                                         __HIP_MEMORY_SCOPE_AGENT) < DOMAIN_BLOCKS)
                    __builtin_amdgcn_s_sleep(1);
            }
            __syncthreads();
        }
    }
}

extern "C" void kernel_launch(void* const* d_in, const int* in_sizes, int n_in,
                              void* d_out, int out_size, void* d_ws, size_t ws_size,
                              hipStream_t stream) {
    const float* x   = (const float*)d_in[0];
    const float* fw  = (const float*)d_in[1];
    const float* tw  = (const float*)d_in[2];
    const float* Wih = (const float*)d_in[3];
    const float* bih = (const float*)d_in[4];
    const float* Whh = (const float*)d_in[5];
    const float* bhh = (const float*)d_in[6];
    float* out = (float*)d_out;

    // zero barrier counters + h exchange buffers every call (graph-replay safe)
    const size_t zero_bytes = CTR_BYTES + (size_t)4 * B_ * H_ * sizeof(float);
    hipMemsetAsync(d_ws, 0, zero_bytes, stream);

    void* kargs[] = { (void*)&x, (void*)&fw, (void*)&tw, (void*)&Wih, (void*)&bih,
                      (void*)&Whh, (void*)&bhh, (void*)&out, (void*)&d_ws };
    hipError_t e = hipLaunchCooperativeKernel((const void*)lstm_mfma,
                                              dim3(NBLK), dim3(NTHR),
                                              kargs, 0, stream);
    if (e != hipSuccess) {
        // fallback: plain launch; 64 blocks at 1 block/CU (LDS-bound) on 256 CUs
        // are trivially co-resident; only device-scope atomics used.
        lstm_mfma<<<dim3(NBLK), dim3(NTHR), 0, stream>>>(
            x, fw, tw, Wih, bih, Whh, bhh, out, d_ws);
    }
}

// Round 5
// 9240.385 us; speedup vs baseline: 9.9017x; 1.0390x over previous
//
#include <hip/hip_runtime.h>
#include <math.h>

#define B_ 128
#define S_ 1024
#define F_ 256
#define H_ 256
#define G3 768

#define UG 8        // unit-groups per layer (32 units each)
#define UNITS 32
#define M_ROWS 96   // 3 gates * 32 units
#define BGROUPS 4
#define BB 32
#define NBLK (BGROUPS * 2 * UG)   // 64 blocks
#define NTHR 256
#define NPHASE (S_ + 1)
#define DOMAIN_BLOCKS (2 * UG)    // 16 blocks per barrier domain

#define CTR_SLOTS (S_ * BGROUPS)
#define CTR_BYTES (CTR_SLOTS * 4)

typedef __bf16 bf16x8 __attribute__((ext_vector_type(8)));
typedef float f32x4 __attribute__((ext_vector_type(4)));
typedef unsigned short us8 __attribute__((ext_vector_type(8)));

__device__ __forceinline__ float sigf(float v) { return 1.0f / (1.0f + __expf(-v)); }
__device__ __forceinline__ float tanh_fast(float v) {
    return __builtin_fmaf(2.0f, sigf(2.0f * v), -1.0f);
}
__device__ __forceinline__ unsigned short f2bf(float f) {
    unsigned u = __builtin_bit_cast(unsigned, f);
    return (unsigned short)((u + 0x7fffu + ((u >> 16) & 1u)) >> 16);   // RNE
}

// coherent (agent-scope, cache-bypassing) 8-byte load of 4 bf16
__device__ __forceinline__ unsigned long long load8_coh(const unsigned short* p) {
    return __hip_atomic_load((unsigned long long*)p, __ATOMIC_RELAXED,
                             __HIP_MEMORY_SCOPE_AGENT);
}
__device__ __forceinline__ void store2_coh(unsigned short* p, unsigned short v) {
    __hip_atomic_store(p, v, __ATOMIC_RELAXED, __HIP_MEMORY_SCOPE_AGENT);
}

__global__ __launch_bounds__(NTHR)
void lstm_mfma(const float* __restrict__ x,    // (B,S,F)
               const float* __restrict__ fw,   // (F)
               const float* __restrict__ tw,   // (S)
               const float* __restrict__ Wih,  // (L,3H,F)
               const float* __restrict__ bih,  // (L,3H)
               const float* __restrict__ Whh,  // (L,3H,H)
               const float* __restrict__ bhh,  // (L,3H)
               float* __restrict__ out,        // outputs | hs | cs
               void* __restrict__ ws)
{
    // fragment-ordered bf16 weights: [mt(6)][kt(16)][lane(64)][8 bf16]
    __shared__ unsigned short sW[6 * 16 * 64 * 8];     // 96 KB
    // fragment-ordered bf16 x-inputs (layer0 only, kt 0..7): [kt(8)][nt(2)][lane(64)][8]
    __shared__ unsigned short sIn[8 * 2 * 64 * 8];     // 16 KB
    __shared__ float sG[M_ROWS][BB + 1];               // gates fp32, padded
    __shared__ float sB[M_ROWS];

    unsigned* ctr = (unsigned*)ws;
    unsigned short* hbuf = (unsigned short*)((char*)ws + CTR_BYTES); // [layer][parity][B][H] bf16
    float* outputs = out;
    float* hs = out + (size_t)B_ * S_ * H_;
    float* cs = hs + (size_t)2 * B_ * H_;

    const int bid   = blockIdx.x;
    const int tid   = threadIdx.x;
    const int ug    = bid & 7;
    const int layer = (bid >> 3) & 1;
    const int bg    = bid >> 4;
    const int gb0   = bg * BB;

    const int lane = tid & 63;
    const int wave = tid >> 6;
    const int ntw  = wave & 1;          // ntile (batch 16-half)
    const int m0   = (wave >> 1) * 3;   // first mtile (of 16 rows)

    const float* Wih_l = Wih + (size_t)layer * G3 * F_;
    const float* Whh_l = Whh + (size_t)layer * G3 * H_;

    // ---- stage weights once into fragment order (bf16) ----
    // A-frag layout (16x16x32): lane holds A[mt*16 + (l&15)][kt*32 + (l>>4)*8 + j]
    for (int idx = tid; idx < 6 * 16 * 64; idx += NTHR) {
        const int l   = idx & 63;
        const int kt  = (idx >> 6) & 15;
        const int mt  = idx >> 10;
        const int row = mt * 16 + (l & 15);              // local gate row 0..95
        const int k   = kt * 32 + (l >> 4) * 8;          // 0..504
        const int grow = (row >> 5) * H_ + ug * UNITS + (row & 31);
        const float* src = (k < 256) ? (Wih_l + (size_t)grow * F_ + k)
                                     : (Whh_l + (size_t)grow * H_ + (k - 256));
        float4 a = *(const float4*)src;
        float4 b = *(const float4*)(src + 4);
        us8 w;
        w[0] = f2bf(a.x); w[1] = f2bf(a.y); w[2] = f2bf(a.z); w[3] = f2bf(a.w);
        w[4] = f2bf(b.x); w[5] = f2bf(b.y); w[6] = f2bf(b.z); w[7] = f2bf(b.w);
        *(us8*)&sW[(size_t)idx * 8] = w;
    }
    if (tid < M_ROWS) {
        const int grow = (tid >> 5) * H_ + ug * UNITS + (tid & 31);
        sB[tid] = bih[layer * G3 + grow] + bhh[layer * G3 + grow];
    }
    __syncthreads();

    float c_reg[4] = {0.f, 0.f, 0.f, 0.f};
    const int uu = tid & 31;   // update: unit
    const int bq = tid >> 5;   // update: batch sub-index

    // fragment source column for this lane (batch row), fragment k-offset
    const int bcol = gb0 + ntw * 16 + (lane & 15);
    const int kofs = (lane >> 4) * 8;

    for (int p = 0; p < NPHASE; ++p) {
        const bool active = (layer == 0) ? (p < S_) : (p >= 1);
        const int par  = p & 1;
        const int prev = par ^ 1;
        const int t    = (layer == 0) ? p : (p - 1);
        unsigned short* hb_own      = hbuf + ((size_t)layer * 2 + par)  * B_ * H_;
        const unsigned short* hb_own_prev = hbuf + ((size_t)layer * 2 + prev) * B_ * H_;
        const unsigned short* hb_l0_prev  = hbuf + ((size_t)prev)             * B_ * H_;

        // ---- load h-side B-fragments direct to registers (coherent bf16) ----
        unsigned long long q[32];
        if (active) {
            if (layer == 0) {
                #pragma unroll
                for (int kt = 8; kt < 16; ++kt) {
                    const int k = kt * 32 + kofs - 256;
                    const unsigned short* src = hb_own_prev + (size_t)bcol * H_ + k;
                    q[2 * kt]     = load8_coh(src);
                    q[2 * kt + 1] = load8_coh(src + 4);
                }
            } else {
                #pragma unroll
                for (int kt = 0; kt < 16; ++kt) {
                    const int k = kt * 32 + kofs;
                    const unsigned short* src = (k < 256)
                        ? (hb_l0_prev  + (size_t)bcol * H_ + k)
                        : (hb_own_prev + (size_t)bcol * H_ + (k - 256));
                    q[2 * kt]     = load8_coh(src);
                    q[2 * kt + 1] = load8_coh(src + 4);
                }
            }
        }

        // ---- layer0: stage x*fw*tw into sIn (kt 0..7) ----
        if (layer == 0) {
            if (active) {
                const float twt = tw[t];
                for (int idx = tid; idx < 8 * 2 * 64; idx += NTHR) {
                    const int l  = idx & 63;
                    const int nt = (idx >> 6) & 1;
                    const int kt = idx >> 7;
                    const int bc = gb0 + nt * 16 + (l & 15);
                    const int k  = kt * 32 + (l >> 4) * 8;
                    const float* src = x + ((size_t)bc * S_ + t) * F_ + k;
                    float4 a = *(const float4*)src;
                    float4 b = *(const float4*)(src + 4);
                    const float4 w1 = *(const float4*)(fw + k);
                    const float4 w2 = *(const float4*)(fw + k + 4);
                    a.x *= w1.x * twt; a.y *= w1.y * twt;
                    a.z *= w1.z * twt; a.w *= w1.w * twt;
                    b.x *= w2.x * twt; b.y *= w2.y * twt;
                    b.z *= w2.z * twt; b.w *= w2.w * twt;
                    us8 w;
                    w[0] = f2bf(a.x); w[1] = f2bf(a.y); w[2] = f2bf(a.z); w[3] = f2bf(a.w);
                    w[4] = f2bf(b.x); w[5] = f2bf(b.y); w[6] = f2bf(b.z); w[7] = f2bf(b.w);
                    *(us8*)&sIn[(size_t)idx * 8] = w;
                }
            }
            __syncthreads();
        }

        if (active) {
            f32x4 acc0 = {0.f, 0.f, 0.f, 0.f};
            f32x4 acc1 = {0.f, 0.f, 0.f, 0.f};
            f32x4 acc2 = {0.f, 0.f, 0.f, 0.f};
            #pragma unroll
            for (int kt = 0; kt < 16; ++kt) {
                bf16x8 bfr;
                if (layer == 0 && kt < 8) {
                    bfr = *(const bf16x8*)&sIn[((kt * 2 + ntw) * 64 + lane) * 8];
                } else {
                    unsigned long long lo = q[2 * kt], hi = q[2 * kt + 1];
                    us8 u;
                    u[0] = (unsigned short)lo;         u[1] = (unsigned short)(lo >> 16);
                    u[2] = (unsigned short)(lo >> 32); u[3] = (unsigned short)(lo >> 48);
                    u[4] = (unsigned short)hi;         u[5] = (unsigned short)(hi >> 16);
                    u[6] = (unsigned short)(hi >> 32); u[7] = (unsigned short)(hi >> 48);
                    bfr = __builtin_bit_cast(bf16x8, u);
                }
                const bf16x8 a0 = *(const bf16x8*)&sW[(((m0 + 0) * 16 + kt) * 64 + lane) * 8];
                const bf16x8 a1 = *(const bf16x8*)&sW[(((m0 + 1) * 16 + kt) * 64 + lane) * 8];
                const bf16x8 a2 = *(const bf16x8*)&sW[(((m0 + 2) * 16 + kt) * 64 + lane) * 8];
                acc0 = __builtin_amdgcn_mfma_f32_16x16x32_bf16(a0, bfr, acc0, 0, 0, 0);
                acc1 = __builtin_amdgcn_mfma_f32_16x16x32_bf16(a1, bfr, acc1, 0, 0, 0);
                acc2 = __builtin_amdgcn_mfma_f32_16x16x32_bf16(a2, bfr, acc2, 0, 0, 0);
            }
            // C/D layout: col = lane&15, row = (lane>>4)*4 + reg
            const int crow = (lane >> 4) * 4;
            const int ccol = ntw * 16 + (lane & 15);
            #pragma unroll
            for (int r = 0; r < 4; ++r) {
                sG[(m0 + 0) * 16 + crow + r][ccol] = acc0[r];
                sG[(m0 + 1) * 16 + crow + r][ccol] = acc1[r];
                sG[(m0 + 2) * 16 + crow + r][ccol] = acc2[r];
            }
        }
        __syncthreads();

        if (active) {
            #pragma unroll
            for (int qq = 0; qq < 4; ++qq) {
                const int b = qq * 8 + bq;
                const float gi = sG[uu][b]      + sB[uu];
                const float gg = sG[32 + uu][b] + sB[32 + uu];
                const float go = sG[64 + uu][b] + sB[64 + uu];
                const float cp = c_reg[qq];
                const float fg = sigf(cp);                 // forget = sigmoid(c_prev)
                const float cn = fg * cp + sigf(gi) * tanh_fast(gg);
                const float hn = sigf(go) * tanh_fast(cn);
                c_reg[qq] = cn;
                const int bglob = gb0 + b;
                const int hg = ug * UNITS + uu;
                store2_coh(hb_own + (size_t)bglob * H_ + hg, f2bf(hn));  // bf16 exchange
                if (layer == 1)
                    outputs[((size_t)bglob * S_ + t) * H_ + hg] = hn;
                if ((layer == 0 && p == S_ - 1) || (layer == 1 && p == S_)) {
                    hs[(size_t)layer * B_ * H_ + (size_t)bglob * H_ + hg] = hn;
                    cs[(size_t)layer * B_ * H_ + (size_t)bglob * H_ + hg] = cn;
                }
            }
        }

        // inter-block barrier per batch-group domain (16 blocks).
        // h-exchange uses agent-scope (coherence-point) ops; vmcnt drain before
        // arrival makes our h visible to all XCDs before the counter bumps.
        if (p < S_) {
            __syncthreads();
            if (tid == 0) {
                const int slot = p * BGROUPS + bg;
                asm volatile("s_waitcnt vmcnt(0)" ::: "memory");
                __hip_atomic_fetch_add(&ctr[slot], 1u, __ATOMIC_RELAXED,
                                       __HIP_MEMORY_SCOPE_AGENT);
                while (__hip_atomic_load(&ctr[slot], __ATOMIC_RELAXED,
                                         __HIP_MEMORY_SCOPE_AGENT) < DOMAIN_BLOCKS)
                    __builtin_amdgcn_s_sleep(1);
            }
            __syncthreads();
        }
    }
}

extern "C" void kernel_launch(void* const* d_in, const int* in_sizes, int n_in,
                              void* d_out, int out_size, void* d_ws, size_t ws_size,
                              hipStream_t stream) {
    const float* x   = (const float*)d_in[0];
    const float* fw  = (const float*)d_in[1];
    const float* tw  = (const float*)d_in[2];
    const float* Wih = (const float*)d_in[3];
    const float* bih = (const float*)d_in[4];
    const float* Whh = (const float*)d_in[5];
    const float* bhh = (const float*)d_in[6];
    float* out = (float*)d_out;

    // zero barrier counters + bf16 h exchange buffers every call (graph-replay safe)
    const size_t zero_bytes = CTR_BYTES + (size_t)4 * B_ * H_ * sizeof(unsigned short);
    hipMemsetAsync(d_ws, 0, zero_bytes, stream);

    void* kargs[] = { (void*)&x, (void*)&fw, (void*)&tw, (void*)&Wih, (void*)&bih,
                      (void*)&Whh, (void*)&bhh, (void*)&out, (void*)&d_ws };
    hipError_t e = hipLaunchCooperativeKernel((const void*)lstm_mfma,
                                              dim3(NBLK), dim3(NTHR),
                                              kargs, 0, stream);
    if (e != hipSuccess) {
        // fallback: plain launch; 64 blocks at 1 block/CU (LDS-bound) on 256 CUs
        // are trivially co-resident; only device-scope atomics used.
        lstm_mfma<<<dim3(NBLK), dim3(NTHR), 0, stream>>>(
            x, fw, tw, Wih, bih, Whh, bhh, out, d_ws);
    }
}

// Round 6
// 9144.512 us; speedup vs baseline: 10.0055x; 1.0105x over previous
//
#include <hip/hip_runtime.h>
#include <math.h>

#define B_ 128
#define S_ 1024
#define F_ 256
#define H_ 256
#define G3 768
#define BH (B_ * H_)

#define UG 8        // unit-groups per layer (32 units each)
#define UNITS 32
#define M_ROWS 96   // 3 gates * 32 units
#define BGROUPS 4
#define BB 32
#define NBLK (BGROUPS * 2 * UG)   // 64 blocks
#define NTHR 256
#define NPHASE (S_ + 1)

// ws layout: [0,4096) prog counters (32 layer1-blocks x 4 waves = 128 u32)
//            [4096, +4*BH*4)  h0 exchange, 4-deep, u32 = (bf16<<16)|tag
//            [...,  +2*BH*4)  h1 exchange, 2-deep
#define PROG_BYTES 4096
#define WS_ZERO_BYTES (PROG_BYTES + (size_t)(4 + 2) * BH * 4)

typedef __bf16 bf16x8 __attribute__((ext_vector_type(8)));
typedef float f32x4 __attribute__((ext_vector_type(4)));
typedef unsigned short us8 __attribute__((ext_vector_type(8)));

__device__ __forceinline__ float sigf(float v) { return 1.0f / (1.0f + __expf(-v)); }
__device__ __forceinline__ float tanh_fast(float v) {
    return __builtin_fmaf(2.0f, sigf(2.0f * v), -1.0f);
}
__device__ __forceinline__ unsigned short f2bf(float f) {
    unsigned u = __builtin_bit_cast(unsigned, f);
    return (unsigned short)((u + 0x7fffu + ((u >> 16) & 1u)) >> 16);   // RNE
}

// Poll-load 8 kt-rows (8 tagged u32 each = 4 u64 each) until every word's
// tag matches. The successful poll IS the data load (tag+data same word).
__device__ __forceinline__ void poll8kt(const unsigned* slab, int bcol, int kofs,
                                        unsigned short tag, unsigned long long* q) {
    const unsigned* base = slab + (size_t)bcol * H_ + kofs;
    bool ok;
    do {
        ok = true;
        #pragma unroll
        for (int kt = 0; kt < 8; ++kt) {
            const unsigned long long* p8 = (const unsigned long long*)(base + kt * 32);
            #pragma unroll
            for (int j = 0; j < 4; ++j) {
                const unsigned long long v = __hip_atomic_load(
                    (unsigned long long*)(p8 + j), __ATOMIC_RELAXED,
                    __HIP_MEMORY_SCOPE_AGENT);
                q[kt * 4 + j] = v;
                ok &= ((unsigned short)v == tag) &
                      ((unsigned short)(v >> 32) == tag);
            }
        }
    } while (!__all(ok));
}

__device__ __forceinline__ bf16x8 unpack8(const unsigned long long* qq) {
    us8 u;
    u[0] = (unsigned short)((unsigned)qq[0] >> 16); u[1] = (unsigned short)(qq[0] >> 48);
    u[2] = (unsigned short)((unsigned)qq[1] >> 16); u[3] = (unsigned short)(qq[1] >> 48);
    u[4] = (unsigned short)((unsigned)qq[2] >> 16); u[5] = (unsigned short)(qq[2] >> 48);
    u[6] = (unsigned short)((unsigned)qq[3] >> 16); u[7] = (unsigned short)(qq[3] >> 48);
    return __builtin_bit_cast(bf16x8, u);
}

__global__ __launch_bounds__(NTHR)
void lstm_df(const float* __restrict__ x,    // (B,S,F)
             const float* __restrict__ fw,   // (F)
             const float* __restrict__ tw,   // (S)
             const float* __restrict__ Wih,  // (L,3H,F)
             const float* __restrict__ bih,  // (L,3H)
             const float* __restrict__ Whh,  // (L,3H,H)
             const float* __restrict__ bhh,  // (L,3H)
             float* __restrict__ out,        // outputs | hs | cs
             void* __restrict__ ws)
{
    // fragment-ordered bf16 weights: [mt(6)][kt(16)][lane(64)][8 bf16]
    __shared__ unsigned short sW[6 * 16 * 64 * 8];     // 96 KB
    // fragment-ordered bf16 x-inputs (layer0, kt 0..7): [kt(8)][nt(2)][lane(64)][8]
    __shared__ unsigned short sIn[8 * 2 * 64 * 8];     // 16 KB
    __shared__ float sG[M_ROWS][BB + 1];               // gates fp32, padded
    __shared__ float sB[M_ROWS];

    unsigned* prog  = (unsigned*)ws;                            // 128 u32
    unsigned* h0buf = (unsigned*)((char*)ws + PROG_BYTES);      // [4][B][H]
    unsigned* h1buf = h0buf + (size_t)4 * BH;                   // [2][B][H]
    float* outputs = out;
    float* hs = out + (size_t)B_ * S_ * H_;
    float* cs = hs + (size_t)2 * B_ * H_;

    const int bid   = blockIdx.x;
    const int tid   = threadIdx.x;
    const int ug    = bid & 7;
    const int layer = (bid >> 3) & 1;
    const int bg    = bid >> 4;
    const int gb0   = bg * BB;

    const int lane = tid & 63;
    const int wave = tid >> 6;
    const int ntw  = wave & 1;          // ntile (batch 16-half)
    const int m0   = (wave >> 1) * 3;   // first mtile (of 16 rows)

    const float* Wih_l = Wih + (size_t)layer * G3 * F_;
    const float* Whh_l = Whh + (size_t)layer * G3 * H_;

    // ---- stage weights once into fragment order (bf16) ----
    // A-frag layout (16x16x32): lane holds A[mt*16 + (l&15)][kt*32 + (l>>4)*8 + j]
    for (int idx = tid; idx < 6 * 16 * 64; idx += NTHR) {
        const int l   = idx & 63;
        const int kt  = (idx >> 6) & 15;
        const int mt  = idx >> 10;
        const int row = mt * 16 + (l & 15);              // local gate row 0..95
        const int k   = kt * 32 + (l >> 4) * 8;          // 0..504
        const int grow = (row >> 5) * H_ + ug * UNITS + (row & 31);
        const float* src = (k < 256) ? (Wih_l + (size_t)grow * F_ + k)
                                     : (Whh_l + (size_t)grow * H_ + (k - 256));
        float4 a = *(const float4*)src;
        float4 b = *(const float4*)(src + 4);
        us8 w;
        w[0] = f2bf(a.x); w[1] = f2bf(a.y); w[2] = f2bf(a.z); w[3] = f2bf(a.w);
        w[4] = f2bf(b.x); w[5] = f2bf(b.y); w[6] = f2bf(b.z); w[7] = f2bf(b.w);
        *(us8*)&sW[(size_t)idx * 8] = w;
    }
    if (tid < M_ROWS) {
        const int grow = (tid >> 5) * H_ + ug * UNITS + (tid & 31);
        sB[tid] = bih[layer * G3 + grow] + bhh[layer * G3 + grow];
    }

    float c_reg[4] = {0.f, 0.f, 0.f, 0.f};
    const int uu = tid & 31;   // update: unit
    const int bq = tid >> 5;   // update: batch sub-index

    // fragment source column (batch row) and k-offset for this lane
    const int bcol = gb0 + ntw * 16 + (lane & 15);
    const int kofs = (lane >> 4) * 8;

    __syncthreads();

    for (int p = 0; p < NPHASE; ++p) {
        const bool active = (layer == 0) ? (p < S_) : (p >= 1);
        const int t = (layer == 0) ? p : (p - 1);

        __syncthreads();   // sG of prev phase fully consumed; safe to rewrite

        if (layer == 0) {
            if (active) {
                const float twt = tw[t];
                for (int idx = tid; idx < 8 * 2 * 64; idx += NTHR) {
                    const int l  = idx & 63;
                    const int nt = (idx >> 6) & 1;
                    const int kt = idx >> 7;
                    const int bc = gb0 + nt * 16 + (l & 15);
                    const int k  = kt * 32 + (l >> 4) * 8;
                    const float* src = x + ((size_t)bc * S_ + t) * F_ + k;
                    float4 a = *(const float4*)src;
                    float4 b = *(const float4*)(src + 4);
                    const float4 w1 = *(const float4*)(fw + k);
                    const float4 w2 = *(const float4*)(fw + k + 4);
                    a.x *= w1.x * twt; a.y *= w1.y * twt;
                    a.z *= w1.z * twt; a.w *= w1.w * twt;
                    b.x *= w2.x * twt; b.y *= w2.y * twt;
                    b.z *= w2.z * twt; b.w *= w2.w * twt;
                    us8 w;
                    w[0] = f2bf(a.x); w[1] = f2bf(a.y); w[2] = f2bf(a.z); w[3] = f2bf(a.w);
                    w[4] = f2bf(b.x); w[5] = f2bf(b.y); w[6] = f2bf(b.z); w[7] = f2bf(b.w);
                    *(us8*)&sIn[(size_t)idx * 8] = w;
                }
            }
            __syncthreads();
        }

        if (active) {
            f32x4 acc0 = {0.f, 0.f, 0.f, 0.f};
            f32x4 acc1 = {0.f, 0.f, 0.f, 0.f};
            f32x4 acc2 = {0.f, 0.f, 0.f, 0.f};
            unsigned long long q[32];

            // ---- pass A: kt 0..7 ----
            if (layer == 1) {
                // h0(t) = h0(p-1): slab (p-1)&3, tag p
                poll8kt(h0buf + (size_t)((p - 1) & 3) * BH, bcol, kofs,
                        (unsigned short)p, q);
                // publish consumption progress (per wave)
                if (lane == 0)
                    __hip_atomic_store(&prog[((bg * 8 + ug) << 2) + wave], (unsigned)p,
                                       __ATOMIC_RELAXED, __HIP_MEMORY_SCOPE_AGENT);
            }
            #pragma unroll
            for (int kt = 0; kt < 8; ++kt) {
                const bf16x8 bfr = (layer == 0)
                    ? *(const bf16x8*)&sIn[((kt * 2 + ntw) * 64 + lane) * 8]
                    : unpack8(&q[kt * 4]);
                const bf16x8 a0 = *(const bf16x8*)&sW[(((m0 + 0) * 16 + kt) * 64 + lane) * 8];
                const bf16x8 a1 = *(const bf16x8*)&sW[(((m0 + 1) * 16 + kt) * 64 + lane) * 8];
                const bf16x8 a2 = *(const bf16x8*)&sW[(((m0 + 2) * 16 + kt) * 64 + lane) * 8];
                acc0 = __builtin_amdgcn_mfma_f32_16x16x32_bf16(a0, bfr, acc0, 0, 0, 0);
                acc1 = __builtin_amdgcn_mfma_f32_16x16x32_bf16(a1, bfr, acc1, 0, 0, 0);
                acc2 = __builtin_amdgcn_mfma_f32_16x16x32_bf16(a2, bfr, acc2, 0, 0, 0);
            }

            // ---- pass B: kt 8..15 (recurrent half) ----
            {
                const unsigned* slab = (layer == 0)
                    ? (h0buf + (size_t)((p - 1) & 3) * BH)     // h0(p-1), tag p
                    : (h1buf + (size_t)((p - 2) & 1) * BH);    // h1(p-2), tag p-1
                const unsigned short tg = (layer == 0) ? (unsigned short)p
                                                       : (unsigned short)(p - 1);
                poll8kt(slab, bcol, kofs, tg, q);
            }
            #pragma unroll
            for (int ktl = 0; ktl < 8; ++ktl) {
                const int kt = 8 + ktl;
                const bf16x8 bfr = unpack8(&q[ktl * 4]);
                const bf16x8 a0 = *(const bf16x8*)&sW[(((m0 + 0) * 16 + kt) * 64 + lane) * 8];
                const bf16x8 a1 = *(const bf16x8*)&sW[(((m0 + 1) * 16 + kt) * 64 + lane) * 8];
                const bf16x8 a2 = *(const bf16x8*)&sW[(((m0 + 2) * 16 + kt) * 64 + lane) * 8];
                acc0 = __builtin_amdgcn_mfma_f32_16x16x32_bf16(a0, bfr, acc0, 0, 0, 0);
                acc1 = __builtin_amdgcn_mfma_f32_16x16x32_bf16(a1, bfr, acc1, 0, 0, 0);
                acc2 = __builtin_amdgcn_mfma_f32_16x16x32_bf16(a2, bfr, acc2, 0, 0, 0);
            }

            // C/D layout: col = lane&15, row = (lane>>4)*4 + reg
            const int crow = (lane >> 4) * 4;
            const int ccol = ntw * 16 + (lane & 15);
            #pragma unroll
            for (int r = 0; r < 4; ++r) {
                sG[(m0 + 0) * 16 + crow + r][ccol] = acc0[r];
                sG[(m0 + 1) * 16 + crow + r][ccol] = acc1[r];
                sG[(m0 + 2) * 16 + crow + r][ccol] = acc2[r];
            }
        }

        // layer0 back-pressure: before overwriting h0(p-4) ensure all layer1
        // consumer waves of this bg have consumed it (prog >= p-3)
        if (layer == 0 && active && p >= 4 && wave == 0) {
            const unsigned need = (unsigned)(p - 3);
            bool ok;
            do {
                const unsigned v = (lane < 32)
                    ? __hip_atomic_load(&prog[bg * 32 + lane], __ATOMIC_RELAXED,
                                        __HIP_MEMORY_SCOPE_AGENT)
                    : need;
                ok = (v >= need);
            } while (!__all(ok));
        }
        __syncthreads();

        if (active) {
            unsigned* hslab = (layer == 0)
                ? (h0buf + (size_t)(p & 3) * BH)          // h0(p), tag p+1
                : (h1buf + (size_t)((p - 1) & 1) * BH);   // h1(p-1), tag p
            const unsigned tagv = (layer == 0) ? (unsigned)(p + 1) : (unsigned)p;
            #pragma unroll
            for (int qq = 0; qq < 4; ++qq) {
                const int b = qq * 8 + bq;
                const float gi = sG[uu][b]      + sB[uu];
                const float gg = sG[32 + uu][b] + sB[32 + uu];
                const float go = sG[64 + uu][b] + sB[64 + uu];
                const float cp = c_reg[qq];
                const float fg = sigf(cp);                 // forget = sigmoid(c_prev)
                const float cn = fg * cp + sigf(gi) * tanh_fast(gg);
                const float hn = sigf(go) * tanh_fast(cn);
                c_reg[qq] = cn;
                const int bglob = gb0 + b;
                const int hg = ug * UNITS + uu;
                const unsigned pack = ((unsigned)f2bf(hn) << 16) | tagv;
                __hip_atomic_store(&hslab[(size_t)bglob * H_ + hg], pack,
                                   __ATOMIC_RELAXED, __HIP_MEMORY_SCOPE_AGENT);
                if (layer == 1)
                    outputs[((size_t)bglob * S_ + t) * H_ + hg] = hn;
                if ((layer == 0 && p == S_ - 1) || (layer == 1 && p == S_)) {
                    hs[(size_t)layer * B_ * H_ + (size_t)bglob * H_ + hg] = hn;
                    cs[(size_t)layer * B_ * H_ + (size_t)bglob * H_ + hg] = cn;
                }
            }
        }
    }
}

extern "C" void kernel_launch(void* const* d_in, const int* in_sizes, int n_in,
                              void* d_out, int out_size, void* d_ws, size_t ws_size,
                              hipStream_t stream) {
    const float* x   = (const float*)d_in[0];
    const float* fw  = (const float*)d_in[1];
    const float* tw  = (const float*)d_in[2];
    const float* Wih = (const float*)d_in[3];
    const float* bih = (const float*)d_in[4];
    const float* Whh = (const float*)d_in[5];
    const float* bhh = (const float*)d_in[6];
    float* out = (float*)d_out;

    // zero prog + tagged h exchange buffers every call (tag 0 == valid h(-1)=0)
    hipMemsetAsync(d_ws, 0, WS_ZERO_BYTES, stream);

    void* kargs[] = { (void*)&x, (void*)&fw, (void*)&tw, (void*)&Wih, (void*)&bih,
                      (void*)&Whh, (void*)&bhh, (void*)&out, (void*)&d_ws };
    hipError_t e = hipLaunchCooperativeKernel((const void*)lstm_df,
                                              dim3(NBLK), dim3(NTHR),
                                              kargs, 0, stream);
    if (e != hipSuccess) {
        // fallback: plain launch; 64 blocks at 1 block/CU (LDS-bound) on 256 CUs
        // are trivially co-resident; exchange uses only device-scope atomics.
        lstm_df<<<dim3(NBLK), dim3(NTHR), 0, stream>>>(
            x, fw, tw, Wih, bih, Whh, bhh, out, d_ws);
    }
}

// Round 7
// 5787.034 us; speedup vs baseline: 15.8104x; 1.5802x over previous
//
#include <hip/hip_runtime.h>
#include <math.h>

#define B_ 128
#define S_ 1024
#define F_ 256
#define H_ 256
#define G3 768

#define UG 8        // unit-groups per layer (32 units each)
#define UNITS 32
#define M_ROWS 96   // 3 gates * 32 units
#define BGROUPS 4
#define BB 32
#define NBLK (BGROUPS * 2 * UG)   // 64 blocks
#define NTHR 256
#define NPHASE (S_ + 1)

// fragment-ordered tagged h exchange:
//   slab[plane(8)][nt(2)][lane(64)][j(8)] u32, u32 = (bf16<<16) | step_tag
//   plane = producer ug; element (unit,b): l=((u>>3)<<4)|(b&15), j=u&7, nt=b>>4
#define PLANE_U32 (8 * 2 * 64 * 8)   // 8192 u32 = 32 KB per (depth,bg) slab
// ws: [0,4096) prog (32 u32 used); h0: 4-deep x 4bg; h1: 2-deep x 4bg
#define PROG_BYTES 4096
#define H0_U32 (4 * BGROUPS * PLANE_U32)
#define H1_U32 (2 * BGROUPS * PLANE_U32)
#define WS_ZERO_BYTES (PROG_BYTES + (size_t)(H0_U32 + H1_U32) * 4)

typedef __bf16 bf16x8 __attribute__((ext_vector_type(8)));
typedef float f32x4 __attribute__((ext_vector_type(4)));
typedef unsigned short us8 __attribute__((ext_vector_type(8)));

__device__ __forceinline__ float sigf(float v) { return 1.0f / (1.0f + __expf(-v)); }
__device__ __forceinline__ float tanh_fast(float v) {
    return __builtin_fmaf(2.0f, sigf(2.0f * v), -1.0f);
}
__device__ __forceinline__ unsigned short f2bf(float f) {
    unsigned u = __builtin_bit_cast(unsigned, f);
    return (unsigned short)((u + 0x7fffu + ((u >> 16) & 1u)) >> 16);   // RNE
}

// poll one 32-B group (8 tagged u32) until every word carries `tag`.
// consecutive threads poll consecutive 32-B groups -> fully coalesced.
__device__ __forceinline__ void poll_group(const unsigned* gsrc, unsigned short tag,
                                           unsigned long long v[4]) {
    const unsigned long long* p = (const unsigned long long*)gsrc;
    bool ok;
    do {
        ok = true;
        #pragma unroll
        for (int j = 0; j < 4; ++j) {
            v[j] = __hip_atomic_load((unsigned long long*)(p + j),
                                     __ATOMIC_RELAXED, __HIP_MEMORY_SCOPE_AGENT);
            ok &= ((unsigned short)v[j] == tag) &
                  ((unsigned short)(v[j] >> 32) == tag);
        }
    } while (!ok);
}

__device__ __forceinline__ us8 pack_hi(const unsigned long long v[4]) {
    us8 u;
    u[0] = (unsigned short)(v[0] >> 16); u[1] = (unsigned short)(v[0] >> 48);
    u[2] = (unsigned short)(v[1] >> 16); u[3] = (unsigned short)(v[1] >> 48);
    u[4] = (unsigned short)(v[2] >> 16); u[5] = (unsigned short)(v[2] >> 48);
    u[6] = (unsigned short)(v[3] >> 16); u[7] = (unsigned short)(v[3] >> 48);
    return u;
}

__global__ __launch_bounds__(NTHR)
void lstm_coal(const float* __restrict__ x,    // (B,S,F)
               const float* __restrict__ fw,   // (F)
               const float* __restrict__ tw,   // (S)
               const float* __restrict__ Wih,  // (L,3H,F)
               const float* __restrict__ bih,  // (L,3H)
               const float* __restrict__ Whh,  // (L,3H,H)
               const float* __restrict__ bhh,  // (L,3H)
               float* __restrict__ out,        // outputs | hs | cs
               void* __restrict__ ws)
{
    // fragment-ordered bf16 weights: [mt(6)][kt(16)][lane(64)][8 bf16]
    __shared__ unsigned short sW[6 * 16 * 64 * 8];     // 96 KB
    // fragment-ordered bf16 inputs, all 16 kt planes: [kt][nt][lane][8]
    __shared__ unsigned short sIn[16 * 2 * 64 * 8];    // 32 KB
    __shared__ float sG[M_ROWS][BB + 1];               // gates fp32, padded
    __shared__ float sB[M_ROWS];

    unsigned* prog  = (unsigned*)ws;                         // prog[bg*8+ug]
    unsigned* h0buf = (unsigned*)((char*)ws + PROG_BYTES);   // [4][bg][plane..]
    unsigned* h1buf = h0buf + H0_U32;                        // [2][bg][plane..]
    float* outputs = out;
    float* hs = out + (size_t)B_ * S_ * H_;
    float* cs = hs + (size_t)2 * B_ * H_;

    const int bid   = blockIdx.x;
    const int tid   = threadIdx.x;
    const int ug    = bid & 7;
    const int layer = (bid >> 3) & 1;
    const int bg    = bid >> 4;
    const int gb0   = bg * BB;

    const int lane = tid & 63;
    const int wave = tid >> 6;
    const int ntw  = wave & 1;          // ntile (batch 16-half)
    const int m0   = (wave >> 1) * 3;   // first mtile (of 16 rows)

    const float* Wih_l = Wih + (size_t)layer * G3 * F_;
    const float* Whh_l = Whh + (size_t)layer * G3 * H_;

    // ---- stage weights once into fragment order (bf16) ----
    // A-frag layout (16x16x32): lane holds A[mt*16 + (l&15)][kt*32 + (l>>4)*8 + j]
    for (int idx = tid; idx < 6 * 16 * 64; idx += NTHR) {
        const int l   = idx & 63;
        const int kt  = (idx >> 6) & 15;
        const int mt  = idx >> 10;
        const int row = mt * 16 + (l & 15);              // local gate row 0..95
        const int k   = kt * 32 + (l >> 4) * 8;          // 0..504
        const int grow = (row >> 5) * H_ + ug * UNITS + (row & 31);
        const float* src = (k < 256) ? (Wih_l + (size_t)grow * F_ + k)
                                     : (Whh_l + (size_t)grow * H_ + (k - 256));
        float4 a = *(const float4*)src;
        float4 b = *(const float4*)(src + 4);
        us8 w;
        w[0] = f2bf(a.x); w[1] = f2bf(a.y); w[2] = f2bf(a.z); w[3] = f2bf(a.w);
        w[4] = f2bf(b.x); w[5] = f2bf(b.y); w[6] = f2bf(b.z); w[7] = f2bf(b.w);
        *(us8*)&sW[(size_t)idx * 8] = w;
    }
    if (tid < M_ROWS) {
        const int grow = (tid >> 5) * H_ + ug * UNITS + (tid & 31);
        sB[tid] = bih[layer * G3 + grow] + bhh[layer * G3 + grow];
    }

    float c_reg[4] = {0.f, 0.f, 0.f, 0.f};
    const int uu = tid & 31;   // update: unit
    const int bq = tid >> 5;   // update: batch sub-index 0..7
    // producer fragment address components for (uu, b)
    const int pl   = ((uu >> 3) << 4);   // l without (b&15)
    const int pj   = uu & 7;

    __syncthreads();

    for (int p = 0; p < NPHASE; ++p) {
        const bool active = (layer == 0) ? (p < S_) : (p >= 1);
        const int t = (layer == 0) ? p : (p - 1);
        const unsigned* h0rd = h0buf + (size_t)(((p - 1) & 3) * BGROUPS + bg) * PLANE_U32;
        const unsigned* h1rd = h1buf + (size_t)(((p - 2) & 1) * BGROUPS + bg) * PLANE_U32;

        // ================= STAGING =================
        if (active) {
            if (layer == 0) {
                // x * fw * tw -> sIn planes 0..7
                const float twt = tw[t];
                for (int idx = tid; idx < 8 * 2 * 64; idx += NTHR) {
                    const int l  = idx & 63;
                    const int nt = (idx >> 6) & 1;
                    const int kt = idx >> 7;
                    const int bc = gb0 + nt * 16 + (l & 15);
                    const int k  = kt * 32 + (l >> 4) * 8;
                    const float* src = x + ((size_t)bc * S_ + t) * F_ + k;
                    float4 a = *(const float4*)src;
                    float4 b = *(const float4*)(src + 4);
                    const float4 w1 = *(const float4*)(fw + k);
                    const float4 w2 = *(const float4*)(fw + k + 4);
                    a.x *= w1.x * twt; a.y *= w1.y * twt;
                    a.z *= w1.z * twt; a.w *= w1.w * twt;
                    b.x *= w2.x * twt; b.y *= w2.y * twt;
                    b.z *= w2.z * twt; b.w *= w2.w * twt;
                    us8 w;
                    w[0] = f2bf(a.x); w[1] = f2bf(a.y); w[2] = f2bf(a.z); w[3] = f2bf(a.w);
                    w[4] = f2bf(b.x); w[5] = f2bf(b.y); w[6] = f2bf(b.z); w[7] = f2bf(b.w);
                    *(us8*)&sIn[(size_t)idx * 8] = w;
                }
                // h0(p-1), tag p -> sIn planes 8..15 (coalesced poll-stage)
                for (int g = tid; g < 1024; g += NTHR) {
                    unsigned long long v[4];
                    poll_group(h0rd + (size_t)g * 8, (unsigned short)p, v);
                    *(us8*)&sIn[(size_t)(1024 + g) * 8] = pack_hi(v);
                }
            } else {
                // h0(p-1), tag p -> planes 0..7 ; h1(p-2), tag p-1 -> planes 8..15
                for (int g = tid; g < 2048; g += NTHR) {
                    unsigned long long v[4];
                    if (g < 1024) {
                        poll_group(h0rd + (size_t)g * 8, (unsigned short)p, v);
                    } else {
                        poll_group(h1rd + (size_t)(g - 1024) * 8,
                                   (unsigned short)(p - 1), v);
                    }
                    *(us8*)&sIn[(size_t)g * 8] = pack_hi(v);
                }
            }
        }
        __syncthreads();

        // layer1: publish "h0 depth (p-1)&3 consumed" (whole block, post-sync)
        if (layer == 1 && active && tid == 0) {
            __hip_atomic_store(&prog[bg * 8 + ug], (unsigned)p,
                               __ATOMIC_RELAXED, __HIP_MEMORY_SCOPE_AGENT);
        }

        // ================= COMPUTE =================
        if (active) {
            f32x4 acc0 = {0.f, 0.f, 0.f, 0.f};
            f32x4 acc1 = {0.f, 0.f, 0.f, 0.f};
            f32x4 acc2 = {0.f, 0.f, 0.f, 0.f};
            #pragma unroll
            for (int kt = 0; kt < 16; ++kt) {
                const bf16x8 bfr = *(const bf16x8*)&sIn[((kt * 2 + ntw) * 64 + lane) * 8];
                const bf16x8 a0 = *(const bf16x8*)&sW[(((m0 + 0) * 16 + kt) * 64 + lane) * 8];
                const bf16x8 a1 = *(const bf16x8*)&sW[(((m0 + 1) * 16 + kt) * 64 + lane) * 8];
                const bf16x8 a2 = *(const bf16x8*)&sW[(((m0 + 2) * 16 + kt) * 64 + lane) * 8];
                acc0 = __builtin_amdgcn_mfma_f32_16x16x32_bf16(a0, bfr, acc0, 0, 0, 0);
                acc1 = __builtin_amdgcn_mfma_f32_16x16x32_bf16(a1, bfr, acc1, 0, 0, 0);
                acc2 = __builtin_amdgcn_mfma_f32_16x16x32_bf16(a2, bfr, acc2, 0, 0, 0);
            }
            // C/D layout: col = lane&15, row = (lane>>4)*4 + reg
            const int crow = (lane >> 4) * 4;
            const int ccol = ntw * 16 + (lane & 15);
            #pragma unroll
            for (int r = 0; r < 4; ++r) {
                sG[(m0 + 0) * 16 + crow + r][ccol] = acc0[r];
                sG[(m0 + 1) * 16 + crow + r][ccol] = acc1[r];
                sG[(m0 + 2) * 16 + crow + r][ccol] = acc2[r];
            }
        }

        // layer0 back-pressure: before overwriting h0 depth p&3 (held tag p-3),
        // all 8 layer1 consumer blocks of this bg must have consumed it.
        if (layer == 0 && active && p >= 4 && wave == 0) {
            const unsigned need = (unsigned)(p - 3);
            bool ok;
            do {
                const unsigned v = (lane < 8)
                    ? __hip_atomic_load(&prog[bg * 8 + lane], __ATOMIC_RELAXED,
                                        __HIP_MEMORY_SCOPE_AGENT)
                    : need;
                ok = (v >= need);
            } while (!__all(ok));
        }
        __syncthreads();

        // ================= UPDATE + TAGGED STORE =================
        if (active) {
            unsigned* hslab = (layer == 0)
                ? (h0buf + (size_t)((p & 3) * BGROUPS + bg) * PLANE_U32)
                : (h1buf + (size_t)(((p - 1) & 1) * BGROUPS + bg) * PLANE_U32);
            const unsigned tagv = (layer == 0) ? (unsigned)(p + 1) : (unsigned)p;
            #pragma unroll
            for (int qq = 0; qq < 4; ++qq) {
                const int b = qq * 8 + bq;
                const float gi = sG[uu][b]      + sB[uu];
                const float gg = sG[32 + uu][b] + sB[32 + uu];
                const float go = sG[64 + uu][b] + sB[64 + uu];
                const float cp = c_reg[qq];
                const float fg = sigf(cp);                 // forget = sigmoid(c_prev)
                const float cn = fg * cp + sigf(gi) * tanh_fast(gg);
                const float hn = sigf(go) * tanh_fast(cn);
                c_reg[qq] = cn;
                const int bglob = gb0 + b;
                const int hg = ug * UNITS + uu;
                // fragment-ordered tagged store: plane=ug, nt=b>>4, l=pl|(b&15), j=pj
                const size_t fo = (size_t)(((ug * 2 + (b >> 4)) * 64 + (pl | (b & 15))) * 8 + pj);
                const unsigned pack = ((unsigned)f2bf(hn) << 16) | tagv;
                __hip_atomic_store(&hslab[fo], pack,
                                   __ATOMIC_RELAXED, __HIP_MEMORY_SCOPE_AGENT);
                if (layer == 1)
                    outputs[((size_t)bglob * S_ + t) * H_ + hg] = hn;
                if ((layer == 0 && p == S_ - 1) || (layer == 1 && p == S_)) {
                    hs[(size_t)layer * B_ * H_ + (size_t)bglob * H_ + hg] = hn;
                    cs[(size_t)layer * B_ * H_ + (size_t)bglob * H_ + hg] = cn;
                }
            }
        }
    }
}

extern "C" void kernel_launch(void* const* d_in, const int* in_sizes, int n_in,
                              void* d_out, int out_size, void* d_ws, size_t ws_size,
                              hipStream_t stream) {
    const float* x   = (const float*)d_in[0];
    const float* fw  = (const float*)d_in[1];
    const float* tw  = (const float*)d_in[2];
    const float* Wih = (const float*)d_in[3];
    const float* bih = (const float*)d_in[4];
    const float* Whh = (const float*)d_in[5];
    const float* bhh = (const float*)d_in[6];
    float* out = (float*)d_out;

    // zero prog + tagged h slabs every call (tag 0 == valid h(-1)=0)
    hipMemsetAsync(d_ws, 0, WS_ZERO_BYTES, stream);

    void* kargs[] = { (void*)&x, (void*)&fw, (void*)&tw, (void*)&Wih, (void*)&bih,
                      (void*)&Whh, (void*)&bhh, (void*)&out, (void*)&d_ws };
    hipError_t e = hipLaunchCooperativeKernel((const void*)lstm_coal,
                                              dim3(NBLK), dim3(NTHR),
                                              kargs, 0, stream);
    if (e != hipSuccess) {
        // fallback: plain launch; 64 blocks at 1 block/CU (LDS-bound) on 256 CUs
        // are trivially co-resident; exchange uses only device-scope atomics.
        lstm_coal<<<dim3(NBLK), dim3(NTHR), 0, stream>>>(
            x, fw, tw, Wih, bih, Whh, bhh, out, d_ws);
    }
}